// Round 4
// baseline (66.593 us; speedup 1.0000x reference)
//
#include <hip/hip_runtime.h>

#define HH 1024
#define WW 1024
#define NPTS 512          // 16 segments * 32 samples = path points = edges
#define ROWS 2            // rows per block
#define TPB 256
#define W_EPS 1e-6f       // drop edges whose row-weight is below this (err <= 512*eps)
#define CAP 32            // per-tile bucket capacity (fallback path if exceeded)

__device__ __forceinline__ float sigmoidf(float z) {
    // 1/(1+exp(-z)); __expf underflows to 0 for very negative z -> sigmoid==1 exactly.
    float e = __expf(-z);
    return __builtin_amdgcn_rcpf(1.0f + e);
}

__global__ __launch_bounds__(TPB) void render_kernel(
    const float* __restrict__ cp,     // 49 x 2 control points
    const float* __restrict__ color,  // 3 floats
    float* __restrict__ out)          // H x W x 4
{
    __shared__ float  cpL[98];
    __shared__ float  colL[3];
    __shared__ float2 pts[NPTS];
    __shared__ float2 actXW[ROWS][NPTS];   // compacted (x_cross, w) per row
    __shared__ int    actTMM[ROWS][NPTS];  // tmin | (tmax+1)<<8
    __shared__ float2 bucket[ROWS][16][CAP];
    __shared__ int    cnt[ROWS][16];
    __shared__ float  satW[ROWS][16];
    __shared__ int    n_act[ROWS];

    const int tid = threadIdx.x;
    const int y0 = blockIdx.x * ROWS;

    // --- 0. stage inputs, zero bucket state ---
    if (tid < 98) cpL[tid] = cp[tid];
    if (tid < 3)  colL[tid] = color[tid];
    if (tid < ROWS) n_act[tid] = 0;
    if (tid < ROWS * 16) ((int*)cnt)[tid] = 0;
    {   // zero buckets so stage-3 can run guard-free to mmax (0*sigma == 0 exactly)
        float4* bz = (float4*)bucket;
        const int NZ = ROWS * 16 * CAP / 2;   // float4 count
        for (int i = tid; i < NZ; i += TPB) bz[i] = make_float4(0.f, 0.f, 0.f, 0.f);
    }
    __syncthreads();

    // --- 1. Bezier path points (2 per thread), row-independent ---
    for (int i = tid; i < NPTS; i += TPB) {
        int seg = i >> 5;
        int j = i & 31;
        float t = (float)j * (1.0f / 31.0f);   // linspace(0,1,32)
        float mt = 1.0f - t;
        int b = 6 * seg;
        float a0 = mt * mt * mt;
        float a1 = 3.0f * mt * mt * t;
        float a2 = 3.0f * mt * t * t;
        float a3 = t * t * t;
        pts[i] = make_float2(
            a0 * cpL[b+0] + a1 * cpL[b+2] + a2 * cpL[b+4] + a3 * cpL[b+6],
            a0 * cpL[b+1] + a1 * cpL[b+3] + a2 * cpL[b+5] + a3 * cpL[b+7]);
    }
    __syncthreads();

    // --- 2. per-(row,edge) weight; compact + classify per 64-px tile ---
    // tile t covers x in [64t, 64t+63].
    //   saturated for all x in tile  <=> xc >= 64t+77   (sigma >= 1-8e-7)
    //   negligible for all x in tile <=> xc <= 64t-14
    for (int k = 0; k < ROWS * NPTS / TPB; ++k) {
        int id = tid + k * TPB;
        int r = id >> 9;                 // NPTS == 512
        int e = id & (NPTS - 1);
        float yf = (float)(y0 + r);
        float2 p = pts[e];
        float2 q = pts[(e + 1) & (NPTS - 1)];
        float dy = q.y - p.y;
        float dx = q.x - p.x;
        float c = (dy > 0.0f) ? 1.0f : ((dy < 0.0f) ? -1.0f : 0.0f);
        if (fabsf(dy) < 1e-6f) c = 0.0f;
        float t = (yf - p.y) * __builtin_amdgcn_rcpf(dy + 1e-8f);
        float vt = sigmoidf(t * 20.0f) * sigmoidf((1.0f - t) * 20.0f);
        float w = vt * c;
        if (fabsf(w) > W_EPS) {
            float xc = fmaf(t, dx, p.x);
            int tmin = (int)ceilf((xc - 77.0f) * 0.015625f);
            tmin = max(0, min(16, tmin));
            int tmax = (int)floorf((xc + 14.0f) * 0.015625f);
            tmax = max(-1, min(15, tmax));
            int idx = atomicAdd(&n_act[r], 1);
            actXW[r][idx] = make_float2(xc, w);
            actTMM[r][idx] = tmin | ((tmax + 1) << 8);
            for (int tt = tmin; tt <= tmax; ++tt) {
                int pos = atomicAdd(&cnt[r][tt], 1);
                if (pos < CAP) bucket[r][tt][pos] = make_float2(xc, w);
            }
        }
    }
    __syncthreads();

    // --- 2c. per-(row,tile) saturated sum: 32 pairs x 8 strided lanes ---
    {
        int pidx = tid >> 3;            // 0..31
        int sub  = tid & 7;
        int r = pidx >> 4;
        int t = pidx & 15;
        float partial = 0.0f;
        int n = n_act[r];
        for (int i = sub; i < n; i += 8) {
            int tmin = actTMM[r][i] & 0xff;
            if (t < tmin) partial += actXW[r][i].y;
        }
        partial += __shfl_down(partial, 4, 8);
        partial += __shfl_down(partial, 2, 8);
        partial += __shfl_down(partial, 1, 8);
        if (sub == 0) satW[r][t] = partial;
    }
    __syncthreads();

    // --- 3. pixel sweep: wave -> (row, tile-half); 2 iters x 4-tile ILP ---
    const int wv = tid >> 6;
    const int lane = tid & 63;
    const int r = wv >> 1;              // row within block
    const int h = wv & 1;               // which 8-tile half
    const float cr = colL[0], cg = colL[1], cb = colL[2];
    float4* orow = ((float4*)out) + (y0 + r) * WW;
    const int n = n_act[r];

    for (int k = 0; k < 2; ++k) {
        const int tb = h * 8 + k * 4;   // tiles tb..tb+3
        float acc0 = satW[r][tb+0], acc1 = satW[r][tb+1];
        float acc2 = satW[r][tb+2], acc3 = satW[r][tb+3];
        const int m0 = cnt[r][tb+0], m1 = cnt[r][tb+1];
        const int m2 = cnt[r][tb+2], m3 = cnt[r][tb+3];
        int mmax = max(max(min(m0,CAP), min(m1,CAP)), max(min(m2,CAP), min(m3,CAP)));
        const float xf0 = (float)(tb * 64 + lane);

        for (int j = 0; j < mmax; ++j) {      // guard-free: padding is (0,0)
            float2 d0 = bucket[r][tb+0][j];
            float2 d1 = bucket[r][tb+1][j];
            float2 d2 = bucket[r][tb+2][j];
            float2 d3 = bucket[r][tb+3][j];
            acc0 = fmaf(d0.y, sigmoidf(d0.x - xf0),            acc0);
            acc1 = fmaf(d1.y, sigmoidf(d1.x - (xf0 +  64.0f)), acc1);
            acc2 = fmaf(d2.y, sigmoidf(d2.x - (xf0 + 128.0f)), acc2);
            acc3 = fmaf(d3.y, sigmoidf(d3.x - (xf0 + 192.0f)), acc3);
        }

        float accs[4] = {acc0, acc1, acc2, acc3};
        const int ms[4] = {m0, m1, m2, m3};
        for (int c = 0; c < 4; ++c) {
            const int t = tb + c;
            if (ms[c] > CAP) {                // rare overflow: exact recompute
                const float xf = (float)(t * 64 + lane);
                float a = satW[r][t];
                for (int i = 0; i < n; ++i) {
                    int tmm = actTMM[r][i];
                    int tmin = tmm & 0xff;
                    int tmax = (tmm >> 8) - 1;
                    if (t < tmin) {
                        a += actXW[r][i].y;
                    } else if (t <= tmax) {
                        float2 d = actXW[r][i];
                        a = fmaf(d.y, sigmoidf(d.x - xf), a);
                    }
                }
                accs[c] = a;
            }
            orow[t * 64 + lane] = make_float4(cr, cg, cb, sigmoidf(4.0f * accs[c]));
        }
    }
}

extern "C" void kernel_launch(void* const* d_in, const int* in_sizes, int n_in,
                              void* d_out, int out_size, void* d_ws, size_t ws_size,
                              hipStream_t stream) {
    const float* cp = (const float*)d_in[0];
    const float* color = (const float*)d_in[1];
    float* out = (float*)d_out;
    render_kernel<<<HH / ROWS, TPB, 0, stream>>>(cp, color, out);
}

// Round 5
// 65.761 us; speedup vs baseline: 1.0126x; 1.0126x over previous
//
#include <hip/hip_runtime.h>

#define HH 1024
#define WW 1024
#define NPTS 512          // 16 segments * 32 samples = path points = edges
#define TPB 1024          // 1 pixel per thread; wave id == 64-px tile id
#define W_EPS 1e-6f       // drop edges whose row-weight is below this (err <= 512*eps)
#define CAP 32            // per-tile bucket capacity (exact fallback if exceeded)

__device__ __forceinline__ float sigmoidf(float z) {
    // 1/(1+exp(-z)); __expf underflows to 0 for very negative z -> sigmoid==1 exactly.
    float e = __expf(-z);
    return __builtin_amdgcn_rcpf(1.0f + e);
}

// Bezier path point i (i in [0,512), wraps): seg = i>>5, t = (i&31)/31
__device__ __forceinline__ float2 bez(const float* cpL, int i) {
    i &= (NPTS - 1);
    int seg = i >> 5;
    int j = i & 31;
    float t = (float)j * (1.0f / 31.0f);
    float mt = 1.0f - t;
    int b = 6 * seg;
    float a0 = mt * mt * mt;
    float a1 = 3.0f * mt * mt * t;
    float a2 = 3.0f * mt * t * t;
    float a3 = t * t * t;
    return make_float2(
        a0 * cpL[b+0] + a1 * cpL[b+2] + a2 * cpL[b+4] + a3 * cpL[b+6],
        a0 * cpL[b+1] + a1 * cpL[b+3] + a2 * cpL[b+5] + a3 * cpL[b+7]);
}

__global__ __launch_bounds__(TPB) void render_kernel(
    const float* __restrict__ cp,     // 49 x 2 control points
    const float* __restrict__ color,  // 3 floats
    float* __restrict__ out)          // H x W x 4
{
    __shared__ float  cpL[98];
    __shared__ float  colL[3];
    __shared__ float2 actXW[NPTS];    // compacted (x_cross, w) for this row
    __shared__ int    actTMM[NPTS];   // tmin | (tmax+1)<<8
    __shared__ float2 bucket[16][CAP];
    __shared__ int    cnt[16];
    __shared__ int    n_act;

    const int tid = threadIdx.x;
    const int y = blockIdx.x;
    const float yf = (float)y;

    // --- 0. stage inputs, zero counters ---
    if (tid < 98) cpL[tid] = cp[tid];
    if (tid < 3)  colL[tid] = color[tid];
    if (tid == 0) n_act = 0;
    if (tid < 16) cnt[tid] = 0;
    __syncthreads();

    // --- 1. per-edge weight for this row; compact + classify per 64-px tile ---
    // tile t covers x in [64t, 64t+63].
    //   saturated for all x in tile  <=> xc >= 64t+77   (sigma >= 1-8e-7)
    //   negligible for all x in tile <=> xc <= 64t-14
    if (tid < NPTS) {
        float2 p = bez(cpL, tid);
        float2 q = bez(cpL, tid + 1);
        float dy = q.y - p.y;
        float dx = q.x - p.x;
        float c = (dy > 0.0f) ? 1.0f : ((dy < 0.0f) ? -1.0f : 0.0f);
        if (fabsf(dy) < 1e-6f) c = 0.0f;
        float t = (yf - p.y) * __builtin_amdgcn_rcpf(dy + 1e-8f);
        float vt = sigmoidf(t * 20.0f) * sigmoidf((1.0f - t) * 20.0f);
        float w = vt * c;
        if (fabsf(w) > W_EPS) {
            float xc = fmaf(t, dx, p.x);
            int tmin = (int)ceilf((xc - 77.0f) * 0.015625f);
            tmin = max(0, min(16, tmin));
            int tmax = (int)floorf((xc + 14.0f) * 0.015625f);
            tmax = max(-1, min(15, tmax));
            int idx = atomicAdd(&n_act, 1);
            actXW[idx] = make_float2(xc, w);
            actTMM[idx] = tmin | ((tmax + 1) << 8);
            for (int tt = tmin; tt <= tmax; ++tt) {
                int pos = atomicAdd(&cnt[tt], 1);
                if (pos < CAP) bucket[tt][pos] = make_float2(xc, w);
            }
        }
    }
    __syncthreads();

    // --- 2. render: wave id == tile id; 1 px per thread ---
    const int t = tid >> 6;           // tile 0..15
    const int lane = tid & 63;
    const int n = n_act;              // block-uniform
    const float xf = (float)(t * 64 + lane);

    // 2a. in-wave saturated sum: sum of w over edges with t < tmin
    float sat = 0.0f;
    for (int i = lane; i < n; i += 64) {
        int tmin = actTMM[i] & 0xff;
        if (t < tmin) sat += actXW[i].y;
    }
    #pragma unroll
    for (int o = 32; o > 0; o >>= 1) sat += __shfl_xor(sat, o);

    // 2b. transition-window evaluation
    float acc;
    const int m = cnt[t];
    if (m <= CAP) {
        acc = sat;
        for (int j = 0; j < m; ++j) {
            float2 d = bucket[t][j];          // wave-uniform broadcast
            acc = fmaf(d.y, sigmoidf(d.x - xf), acc);
        }
    } else {
        // rare overflow: exact classified scan of the full compact list
        acc = 0.0f;
        for (int i = 0; i < n; ++i) {
            int tmm = actTMM[i];
            int tmin = tmm & 0xff;
            int tmax = (tmm >> 8) - 1;
            if (t < tmin) {
                acc += actXW[i].y;
            } else if (t <= tmax) {
                float2 d = actXW[i];
                acc = fmaf(d.y, sigmoidf(d.x - xf), acc);
            }
        }
    }

    float4* orow = ((float4*)out) + y * WW;
    orow[tid] = make_float4(colL[0], colL[1], colL[2], sigmoidf(4.0f * acc));
}

extern "C" void kernel_launch(void* const* d_in, const int* in_sizes, int n_in,
                              void* d_out, int out_size, void* d_ws, size_t ws_size,
                              hipStream_t stream) {
    const float* cp = (const float*)d_in[0];
    const float* color = (const float*)d_in[1];
    float* out = (float*)d_out;
    render_kernel<<<HH, TPB, 0, stream>>>(cp, color, out);
}